// Round 6
// baseline (494.058 us; speedup 1.0000x reference)
//
#include <hip/hip_runtime.h>
#include <math.h>

// Problem constants (fixed by reference)
#define BB   8
#define LL   512
#define DD   512
#define GG   8
#define SSS  4
#define FGC  4
#define FEC  64
#define EEC  32
#define DHC  256
#define RHC  256
#define NT   (BB*LL)   // 4096 tokens
#define TM   32        // tokens per expert-GEMM tile
#define T4   4         // tokens per routing_main block
#define RGH_M 16       // tokens per gh_glog block

#define XC_STRIDE 264  // shorts per k8 group in Xc (32*8 + 8 pad)
#define HP_STRIDE 272  // shorts per h8 group in Hp (32*8 + 16 pad)

typedef __attribute__((ext_vector_type(8))) short short8;
typedef __attribute__((ext_vector_type(4))) float floatx4;

__device__ __forceinline__ float gelu_exact(float x) {
    return 0.5f * x * (1.0f + erff(x * 0.70710678118654752440f));
}

__device__ __forceinline__ short bf16_rne(float f) {
    union { float f; unsigned u; } a; a.f = f;
    unsigned u = a.u;
    return (short)((u + 0x7fffu + ((u >> 16) & 1u)) >> 16);
}

__device__ __forceinline__ floatx4 mfma16(short8 a, short8 b, floatx4 c) {
    return __builtin_amdgcn_mfma_f32_16x16x32_bf16(a, b, c, 0, 0, 0);
}

// ---------------------------------------------------------------------------
// Pack fp32 weight [e][K][N] -> bf16 [e][K/8][N][8] (B-fragment native:
// lane n's 8 consecutive k contiguous = one 16 B load). Launched only when
// ws_size is large enough to hold the packed buffers.
// ---------------------------------------------------------------------------
__global__ __launch_bounds__(256) void pack_weights(
    const float* __restrict__ in, short* __restrict__ out, int K, int N)
{
    int idx = blockIdx.x * 256 + threadIdx.x;        // (e*(K/8)+k8)*N + n
    int total = EEC * (K >> 3) * N;
    if (idx >= total) return;
    int n   = idx % N;
    int ek8 = idx / N;
    const float* src = in + (size_t)ek8 * 8 * N + n;
    short8 v;
    #pragma unroll
    for (int j = 0; j < 8; ++j) v[j] = bf16_rne(src[(size_t)j * N]);
    *(short8*)(out + (size_t)idx * 8) = v;
}

// ---------------------------------------------------------------------------
// Routing stage A: gh = gelu(hidden @ Wr1 + br1) and glog = gh @ Wr2 + br2.
// fp32 tiled GEMM, 16 tokens x 256 cols x K=512 per block, 512 threads.
// Deterministic in-block glog reduction -> glog_ws (fp32-exact topk inputs).
// ---------------------------------------------------------------------------
__global__ __launch_bounds__(512) void gh_glog_kernel(
    const float* __restrict__ hidden,
    const float* __restrict__ Wr1, const float* __restrict__ br1,
    const float* __restrict__ Wr2, const float* __restrict__ br2,
    float* __restrict__ glog_out)
{
    const int t0  = blockIdx.x * RGH_M;
    const int tid = threadIdx.x;
    const int nl  = tid & 63;     // col lane: cols nl + 64j, j<4
    const int ml  = tid >> 6;     // row lane: rows ml, ml+8

    __shared__ float hs[RGH_M][68];     // K-chunk 64, +4 pad
    __shared__ float ghs[RGH_M][260];   // gh tile, +4 pad

    float acc[2][4];
    #pragma unroll
    for (int i = 0; i < 2; ++i)
        #pragma unroll
        for (int j = 0; j < 4; ++j) acc[i][j] = 0.f;

    for (int kc = 0; kc < DD; kc += 64) {
        __syncthreads();
        {   // stage 16x64 chunk: 1024 floats / 512 thr = float2 each
            int r  = tid >> 5;          // 0..15
            int c2 = (tid & 31) * 2;    // 0..62
            float2 v = *(const float2*)(hidden + (size_t)(t0 + r)*DD + kc + c2);
            hs[r][c2]   = v.x;
            hs[r][c2+1] = v.y;
        }
        __syncthreads();
        #pragma unroll 4
        for (int k = 0; k < 64; ++k) {
            const float* wr = Wr1 + (size_t)(kc + k)*RHC + nl;
            float w0 = wr[0], w1 = wr[64], w2 = wr[128], w3 = wr[192];
            float a0 = hs[ml][k], a1 = hs[ml + 8][k];
            acc[0][0] += a0*w0; acc[0][1] += a0*w1; acc[0][2] += a0*w2; acc[0][3] += a0*w3;
            acc[1][0] += a1*w0; acc[1][1] += a1*w1; acc[1][2] += a1*w2; acc[1][3] += a1*w3;
        }
    }
    __syncthreads();
    #pragma unroll
    for (int i = 0; i < 2; ++i) {
        int r = ml + 8*i;
        #pragma unroll
        for (int j = 0; j < 4; ++j) {
            int c = nl + 64*j;
            ghs[r][c] = gelu_exact(acc[i][j] + br1[c]);
        }
    }
    __syncthreads();
    if (tid < RGH_M*GG) {   // 128 threads: (t,g)
        int t = tid >> 3, g = tid & 7;
        float s = br2[g];
        #pragma unroll 4
        for (int h = 0; h < RHC; ++h) s += ghs[t][h] * Wr2[h*GG + g];
        glog_out[(size_t)(t0 + t)*GG + g] = s;
    }
}

// ---------------------------------------------------------------------------
// Routing stage B: femb, score, ilog, both topk-softmaxes, bucket append,
// y zeroing. T4=4 tokens/block -> grid 1024, LDS ~18 KB (high occupancy).
// All fp32; per-token topk semantics identical to passing rounds.
// ---------------------------------------------------------------------------
__global__ __launch_bounds__(256) void routing_main(
    const float* __restrict__ hidden, const float* __restrict__ feat,
    const float* __restrict__ Wfe, const float* __restrict__ bfe,
    const float* __restrict__ Win_h, const float* __restrict__ Win_f,
    const float* __restrict__ bin_b,
    const float* __restrict__ glog_ws,
    int* __restrict__ bucket_tok, float* __restrict__ bucket_w,
    int* __restrict__ counts,
    float* __restrict__ y)
{
    const int t0  = blockIdx.x * T4;
    const int tid = threadIdx.x;

    __shared__ float hsb[T4][DD];        // 8 KB
    __shared__ float fembb[T4][GG*FEC];  // 8 KB
    __shared__ float featb[T4][GG*FGC];
    __shared__ float part[256];
    __shared__ float glogb[T4][GG];
    __shared__ float gwvb[T4][GG];
    __shared__ float scoreb[T4][GG];
    __shared__ float ilogb[T4][GG*SSS];
    __shared__ float cwvb[T4][GG*SSS];

    for (int i = tid; i < T4*DD; i += 256) {
        int r = i >> 9, c = i & 511;
        hsb[r][c] = hidden[(size_t)(t0 + r)*DD + c];
        y[(size_t)(t0 + r)*DD + c] = 0.0f;
    }
    if (tid < T4*GG*FGC) {   // 128
        int r = tid >> 5, c = tid & 31;
        featb[r][c] = feat[(t0 + r)*(GG*FGC) + c];
    }
    if (tid < T4*GG) {       // 32: glog from stage A
        int t = tid >> 3, g = tid & 7;
        glogb[t][g] = glog_ws[(size_t)(t0 + t)*GG + g];
    }
    __syncthreads();

    // femb
    for (int i = tid; i < T4*GG*FEC; i += 256) {
        int t = i >> 9, col = i & 511;
        int g = col >> 6, e = col & 63;
        const float* wf = Wfe + g*(FGC*FEC) + e;
        fembb[t][col] = bfe[g*FEC + e]
            + featb[t][g*4+0]*wf[0]     + featb[t][g*4+1]*wf[FEC]
            + featb[t][g*4+2]*wf[2*FEC] + featb[t][g*4+3]*wf[3*FEC];
    }
    if (tid < T4*GG) {
        int t = tid >> 3, g = tid & 7;
        float s = 0.f;
        #pragma unroll
        for (int f = 0; f < FGC; ++f) s += fminf(fmaxf(featb[t][g*4+f], 0.f), 1.f);
        scoreb[t][g] = s * 0.25f;
    }
    __syncthreads();

    // ilog halves: thread = (t, gs, half)
    {
        int t = tid >> 6, gs = (tid >> 1) & 31, half = tid & 1;
        int g = gs >> 2, s = gs & 3;
        const float* wh = Win_h + (size_t)g*DD*SSS + s;
        float p = 0.f;
        int d0 = half*256;
        #pragma unroll 4
        for (int d = d0; d < d0 + 256; ++d) p += hsb[t][d] * wh[d*SSS];
        const float* wf = Win_f + (size_t)g*FEC*SSS + s;
        int e0 = half*32;
        #pragma unroll 4
        for (int e = e0; e < e0 + 32; ++e) p += fembb[t][g*FEC + e] * wf[e*SSS];
        part[tid] = p;
    }
    __syncthreads();
    if (tid < T4*GG*SSS) {   // 128
        int t = tid >> 5, gs = tid & 31;
        int g = gs >> 2, s = gs & 3;
        const float centers[4] = {0.0f, 1.0f/3.0f, 2.0f/3.0f, 1.0f};
        float diff = scoreb[t][g] - centers[s];
        ilogb[t][gs] = part[t*64 + gs*2] + part[t*64 + gs*2 + 1]
                     + bin_b[gs] - 16.0f * diff * diff;
    }
    __syncthreads();

    // group top-2 softmax per token
    if (tid < T4) {
        int t = tid;
        float a = -INFINITY, b = -INFINITY;
        #pragma unroll
        for (int g = 0; g < GG; ++g) {
            float v = glogb[t][g];
            if (v > a) { b = a; a = v; } else if (v > b) { b = v; }
        }
        float thresh = b, m = a, sum = 0.f;
        float ex[GG];
        #pragma unroll
        for (int g = 0; g < GG; ++g) {
            float v = glogb[t][g];
            ex[g] = (v >= thresh) ? __expf(v - m) : 0.f;
            sum += ex[g];
        }
        float inv = 1.0f / sum;
        #pragma unroll
        for (int g = 0; g < GG; ++g) gwvb[t][g] = ex[g] * inv;
    }
    // stage top-2 softmax per (t,g)
    if (tid < T4*GG) {
        int t = tid >> 3, g = tid & 7;
        float vv[4] = {ilogb[t][g*4+0], ilogb[t][g*4+1], ilogb[t][g*4+2], ilogb[t][g*4+3]};
        float a = -INFINITY, b = -INFINITY;
        #pragma unroll
        for (int s = 0; s < 4; ++s) {
            float v = vv[s];
            if (v > a) { b = a; a = v; } else if (v > b) { b = v; }
        }
        float thresh = b, m = a, sum = 0.f;
        float ex[4];
        #pragma unroll
        for (int s = 0; s < 4; ++s) {
            ex[s] = (vv[s] >= thresh) ? __expf(vv[s] - m) : 0.f;
            sum += ex[s];
        }
        float inv = 1.0f / sum;
        #pragma unroll
        for (int s = 0; s < 4; ++s) cwvb[t][g*4 + s] = ex[s] * inv;
    }
    __syncthreads();

    if (tid < T4) {
        int t = tid;
        for (int g = 0; g < GG; ++g) {
            float gw = gwvb[t][g];
            if (gw > 0.f) {
                for (int s = 0; s < SSS; ++s) {
                    float w = gw * cwvb[t][g*4 + s];
                    if (w > 0.f) {
                        int ee = g*SSS + s;
                        int pos = atomicAdd(&counts[ee], 1);
                        bucket_tok[ee*NT + pos] = t0 + t;
                        bucket_w[ee*NT + pos]   = w;
                    }
                }
            }
        }
    }
}

// ---------------------------------------------------------------------------
// Expert GEMM, packed-weights path: B-fragment = ONE 16 B load, no cvt VALU.
// Block = (expert, 32-token tile), 4 waves. LDS ~22 KB.
// ---------------------------------------------------------------------------
__global__ __launch_bounds__(256) void expert_mfma_packed(
    const float* __restrict__ hidden,
    const short* __restrict__ We1p, const float* __restrict__ be1,
    const short* __restrict__ We2p, const float* __restrict__ be2,
    const int* __restrict__ bucket_tok, const float* __restrict__ bucket_w,
    const int* __restrict__ counts,
    float* __restrict__ y)
{
    const int e   = blockIdx.y;
    const int cnt = counts[e];
    const int r0  = blockIdx.x * TM;
    if (r0 >= cnt) return;
    const int nrow = min(TM, cnt - r0);
    const int tid  = threadIdx.x;
    const int wave = tid >> 6;
    const int lane = tid & 63;
    const int lm   = lane & 15;
    const int quad = lane >> 4;

    __shared__ short Xc[8 * XC_STRIDE];
    __shared__ short Hp[32 * HP_STRIDE];
    __shared__ int   toks[TM];
    __shared__ float tws[TM];

    if (tid < TM) {
        if (tid < nrow) {
            toks[tid] = bucket_tok[e*NT + r0 + tid];
            tws[tid]  = bucket_w[e*NT + r0 + tid];
        } else { toks[tid] = -1; tws[tid] = 0.f; }
    }
    __syncthreads();

    floatx4 acc[2][4];
    #pragma unroll
    for (int mb = 0; mb < 2; ++mb)
        #pragma unroll
        for (int nb = 0; nb < 4; ++nb)
            acc[mb][nb] = (floatx4){0.f, 0.f, 0.f, 0.f};

    const short* B1 = We1p + (size_t)e * DD * DHC;   // [K/8][256][8]
    const int xr = tid & 31;
    const int xc = tid >> 5;

    for (int kc = 0; kc < DD; kc += 64) {
        __syncthreads();
        {
            const int tk = toks[xr];
            float4 v0 = make_float4(0.f,0.f,0.f,0.f), v1 = v0;
            if (tk >= 0) {
                const float* src = hidden + (size_t)tk*DD + kc + xc*8;
                v0 = *(const float4*)src;
                v1 = *(const float4*)(src + 4);
            }
            short8 xv;
            xv[0]=bf16_rne(v0.x); xv[1]=bf16_rne(v0.y); xv[2]=bf16_rne(v0.z); xv[3]=bf16_rne(v0.w);
            xv[4]=bf16_rne(v1.x); xv[5]=bf16_rne(v1.y); xv[6]=bf16_rne(v1.z); xv[7]=bf16_rne(v1.w);
            *(short8*)(&Xc[xc * XC_STRIDE + xr * 8]) = xv;
        }
        __syncthreads();
        #pragma unroll
        for (int kk = 0; kk < 64; kk += 32) {
            const int k8l = (kk >> 3) + quad;
            short8 a0 = *(const short8*)(&Xc[k8l * XC_STRIDE + lm * 8]);
            short8 a1 = *(const short8*)(&Xc[k8l * XC_STRIDE + (16 + lm) * 8]);
            const int k8 = ((kc + kk) >> 3) + quad;
            #pragma unroll
            for (int nb = 0; nb < 4; ++nb) {
                const int n = wave*64 + nb*16 + lm;
                short8 b = *(const short8*)(B1 + ((size_t)k8 * DHC + n) * 8);
                acc[0][nb] = mfma16(a0, b, acc[0][nb]);
                acc[1][nb] = mfma16(a1, b, acc[1][nb]);
            }
        }
    }

    __syncthreads();
    #pragma unroll
    for (int nb = 0; nb < 4; ++nb) {
        const int h = wave*64 + nb*16 + lm;
        const float b1 = be1[e*DHC + h];
        #pragma unroll
        for (int mb = 0; mb < 2; ++mb) {
            #pragma unroll
            for (int r = 0; r < 4; ++r) {
                const int m = mb*16 + quad*4 + r;
                Hp[(h >> 3) * HP_STRIDE + m * 8 + (h & 7)] =
                    bf16_rne(gelu_exact(acc[mb][nb][r] + b1));
            }
        }
    }
    __syncthreads();

    floatx4 c[2][8];
    #pragma unroll
    for (int mb = 0; mb < 2; ++mb)
        #pragma unroll
        for (int nb = 0; nb < 8; ++nb)
            c[mb][nb] = (floatx4){0.f, 0.f, 0.f, 0.f};

    const short* B2 = We2p + (size_t)e * DHC * DD;   // [256/8][512][8]
    for (int kc = 0; kc < DHC; kc += 32) {
        const int k8 = (kc >> 3) + quad;
        short8 a0 = *(const short8*)(&Hp[k8 * HP_STRIDE + lm * 8]);
        short8 a1 = *(const short8*)(&Hp[k8 * HP_STRIDE + (16 + lm) * 8]);
        #pragma unroll
        for (int nb = 0; nb < 8; ++nb) {
            const int n = wave*128 + nb*16 + lm;
            short8 b = *(const short8*)(B2 + ((size_t)k8 * DD + n) * 8);
            c[0][nb] = mfma16(a0, b, c[0][nb]);
            c[1][nb] = mfma16(a1, b, c[1][nb]);
        }
    }

    #pragma unroll
    for (int nb = 0; nb < 8; ++nb) {
        const int col = wave*128 + nb*16 + lm;
        const float b2 = be2[e*DD + col];
        #pragma unroll
        for (int mb = 0; mb < 2; ++mb) {
            #pragma unroll
            for (int r = 0; r < 4; ++r) {
                const int m = mb*16 + quad*4 + r;
                const int tk = toks[m];
                if (tk >= 0)
                    atomicAdd(&y[(size_t)tk*DD + col], tws[m] * (c[mb][nb][r] + b2));
            }
        }
    }
}

// ---------------------------------------------------------------------------
// Expert GEMM, fallback path (small ws): round-5-proven kernel verbatim.
// ---------------------------------------------------------------------------
__global__ __launch_bounds__(256) void expert_mfma(
    const float* __restrict__ hidden,
    const float* __restrict__ We1, const float* __restrict__ be1,
    const float* __restrict__ We2, const float* __restrict__ be2,
    const int* __restrict__ bucket_tok, const float* __restrict__ bucket_w,
    const int* __restrict__ counts,
    float* __restrict__ y)
{
    const int e   = blockIdx.y;
    const int cnt = counts[e];
    const int r0  = blockIdx.x * TM;
    if (r0 >= cnt) return;
    const int nrow = min(TM, cnt - r0);
    const int tid  = threadIdx.x;
    const int wave = tid >> 6;
    const int lane = tid & 63;
    const int lm   = lane & 15;
    const int quad = lane >> 4;

    __shared__ short Xc[8 * XC_STRIDE];
    __shared__ short Hp[32 * HP_STRIDE];
    __shared__ int   toks[TM];
    __shared__ float tws[TM];

    if (tid < TM) {
        if (tid < nrow) {
            toks[tid] = bucket_tok[e*NT + r0 + tid];
            tws[tid]  = bucket_w[e*NT + r0 + tid];
        } else { toks[tid] = -1; tws[tid] = 0.f; }
    }
    __syncthreads();

    floatx4 acc[2][4];
    #pragma unroll
    for (int mb = 0; mb < 2; ++mb)
        #pragma unroll
        for (int nb = 0; nb < 4; ++nb)
            acc[mb][nb] = (floatx4){0.f, 0.f, 0.f, 0.f};

    const float* W1 = We1 + (size_t)e * DD * DHC;
    const int xr = tid & 31;
    const int xc = tid >> 5;

    for (int kc = 0; kc < DD; kc += 64) {
        __syncthreads();
        {
            const int tk = toks[xr];
            float4 v0 = make_float4(0.f,0.f,0.f,0.f), v1 = v0;
            if (tk >= 0) {
                const float* src = hidden + (size_t)tk*DD + kc + xc*8;
                v0 = *(const float4*)src;
                v1 = *(const float4*)(src + 4);
            }
            short8 xv;
            xv[0]=bf16_rne(v0.x); xv[1]=bf16_rne(v0.y); xv[2]=bf16_rne(v0.z); xv[3]=bf16_rne(v0.w);
            xv[4]=bf16_rne(v1.x); xv[5]=bf16_rne(v1.y); xv[6]=bf16_rne(v1.z); xv[7]=bf16_rne(v1.w);
            *(short8*)(&Xc[xc * XC_STRIDE + xr * 8]) = xv;
        }
        __syncthreads();
        #pragma unroll
        for (int kk = 0; kk < 64; kk += 32) {
            const int k8l = (kk >> 3) + quad;
            short8 a0 = *(const short8*)(&Xc[k8l * XC_STRIDE + lm * 8]);
            short8 a1 = *(const short8*)(&Xc[k8l * XC_STRIDE + (16 + lm) * 8]);
            const int k0 = kc + k8l*8;
            #pragma unroll
            for (int nb = 0; nb < 4; ++nb) {
                const int n = wave*64 + nb*16 + lm;
                const float* src = W1 + (size_t)k0*DHC + n;
                short8 b;
                #pragma unroll
                for (int j = 0; j < 8; ++j) b[j] = bf16_rne(src[(size_t)j*DHC]);
                acc[0][nb] = mfma16(a0, b, acc[0][nb]);
                acc[1][nb] = mfma16(a1, b, acc[1][nb]);
            }
        }
    }

    __syncthreads();
    #pragma unroll
    for (int nb = 0; nb < 4; ++nb) {
        const int h = wave*64 + nb*16 + lm;
        const float b1 = be1[e*DHC + h];
        #pragma unroll
        for (int mb = 0; mb < 2; ++mb) {
            #pragma unroll
            for (int r = 0; r < 4; ++r) {
                const int m = mb*16 + quad*4 + r;
                Hp[(h >> 3) * HP_STRIDE + m * 8 + (h & 7)] =
                    bf16_rne(gelu_exact(acc[mb][nb][r] + b1));
            }
        }
    }
    __syncthreads();

    floatx4 c[2][8];
    #pragma unroll
    for (int mb = 0; mb < 2; ++mb)
        #pragma unroll
        for (int nb = 0; nb < 8; ++nb)
            c[mb][nb] = (floatx4){0.f, 0.f, 0.f, 0.f};

    const float* W2 = We2 + (size_t)e * DHC * DD;

    for (int kc = 0; kc < DHC; kc += 32) {
        const int k8 = (kc >> 3) + quad;
        short8 a0 = *(const short8*)(&Hp[k8 * HP_STRIDE + lm * 8]);
        short8 a1 = *(const short8*)(&Hp[k8 * HP_STRIDE + (16 + lm) * 8]);
        const int k0 = k8*8;
        #pragma unroll
        for (int nb = 0; nb < 8; ++nb) {
            const int n = wave*128 + nb*16 + lm;
            const float* src = W2 + (size_t)k0*DD + n;
            short8 b;
            #pragma unroll
            for (int j = 0; j < 8; ++j) b[j] = bf16_rne(src[(size_t)j*DD]);
            c[0][nb] = mfma16(a0, b, c[0][nb]);
            c[1][nb] = mfma16(a1, b, c[1][nb]);
        }
    }

    #pragma unroll
    for (int nb = 0; nb < 8; ++nb) {
        const int col = wave*128 + nb*16 + lm;
        const float b2 = be2[e*DD + col];
        #pragma unroll
        for (int mb = 0; mb < 2; ++mb) {
            #pragma unroll
            for (int r = 0; r < 4; ++r) {
                const int m = mb*16 + quad*4 + r;
                const int tk = toks[m];
                if (tk >= 0)
                    atomicAdd(&y[(size_t)tk*DD + col], tws[m] * (c[mb][nb][r] + b2));
            }
        }
    }
}

extern "C" void kernel_launch(void* const* d_in, const int* in_sizes, int n_in,
                              void* d_out, int out_size, void* d_ws, size_t ws_size,
                              hipStream_t stream) {
    const float* hidden = (const float*)d_in[0];
    const float* feat   = (const float*)d_in[1];
    // d_in[2] = valid_mask (unused)
    const float* Wr1    = (const float*)d_in[3];
    const float* br1    = (const float*)d_in[4];
    const float* Wr2    = (const float*)d_in[5];
    const float* br2    = (const float*)d_in[6];
    const float* Wfe    = (const float*)d_in[7];
    const float* bfe    = (const float*)d_in[8];
    const float* Win_h  = (const float*)d_in[9];
    const float* Win_f  = (const float*)d_in[10];
    const float* bin_b  = (const float*)d_in[11];
    const float* We1    = (const float*)d_in[12];
    const float* be1    = (const float*)d_in[13];
    const float* We2    = (const float*)d_in[14];
    const float* be2    = (const float*)d_in[15];
    float* y = (float*)d_out;

    // workspace layout: small region first (proven sizes), packed weights after
    char* ws = (char*)d_ws;
    int*   bucket_tok = (int*)ws;             ws += (size_t)EEC*NT*sizeof(int);    // 512 KB
    float* bucket_w   = (float*)ws;           ws += (size_t)EEC*NT*sizeof(float);  // 512 KB
    float* glog_ws    = (float*)ws;           ws += (size_t)NT*GG*sizeof(float);   // 128 KB
    int*   counts     = (int*)ws;             ws += 256;
    short* We1p       = (short*)ws;           ws += (size_t)EEC*DD*DHC*sizeof(short); // 8 MB
    short* We2p       = (short*)ws;
    const size_t need_big = (size_t)EEC*NT*8 + (size_t)NT*GG*4 + 256
                          + (size_t)EEC*DD*DHC*4;   // ~18 MB
    const bool big = (ws_size >= need_big);

    hipMemsetAsync(counts, 0, EEC*sizeof(int), stream);

    if (big) {
        int total1 = EEC * (DD >> 3) * DHC;
        pack_weights<<<(total1 + 255)/256, 256, 0, stream>>>(We1, We1p, DD, DHC);
        int total2 = EEC * (DHC >> 3) * DD;
        pack_weights<<<(total2 + 255)/256, 256, 0, stream>>>(We2, We2p, DHC, DD);
    }

    gh_glog_kernel<<<NT/RGH_M, 512, 0, stream>>>(hidden, Wr1, br1, Wr2, br2, glog_ws);

    routing_main<<<NT/T4, 256, 0, stream>>>(hidden, feat, Wfe, bfe,
                                            Win_h, Win_f, bin_b, glog_ws,
                                            bucket_tok, bucket_w, counts, y);

    dim3 grid2((NT + TM - 1)/TM, EEC);
    if (big) {
        expert_mfma_packed<<<grid2, 256, 0, stream>>>(hidden, We1p, be1, We2p, be2,
                                                      bucket_tok, bucket_w, counts, y);
    } else {
        expert_mfma<<<grid2, 256, 0, stream>>>(hidden, We1, be1, We2, be2,
                                               bucket_tok, bucket_w, counts, y);
    }
}

// Round 7
// 491.980 us; speedup vs baseline: 1.0042x; 1.0042x over previous
//
#include <hip/hip_runtime.h>
#include <hip/hip_bf16.h>
#include <math.h>

// Problem constants (fixed by reference)
#define BB   8
#define LL   512
#define DD   512
#define GG   8
#define SSS  4
#define FGC  4
#define FEC  64
#define EEC  32
#define DHC  256
#define RHC  256
#define NT   (BB*LL)   // 4096 tokens
#define TM   64        // tokens per expert-GEMM tile (512 threads, 8 waves)
#define TI   8         // tokens per ilog_route block
#define RGH_M 16       // tokens per gh_glog block

#define XC2_STRIDE 520 // shorts per k8 group in Xc (64*8 + 8 pad)
#define HP2_STRIDE 520 // shorts per h8 group in Hp (64*8 + 8 pad)

typedef __attribute__((ext_vector_type(8))) short short8;
typedef __attribute__((ext_vector_type(4))) float floatx4;

__device__ __forceinline__ float gelu_exact(float x) {
    return 0.5f * x * (1.0f + erff(x * 0.70710678118654752440f));
}

// HW packed fp32->bf16 RNE (v_cvt_pk_bf16_f32); low 16 bits = first arg
__device__ __forceinline__ unsigned pk2(float a, float b) {
    union { __hip_bfloat162 h; unsigned u; } cv;
    cv.h = __float22bfloat162_rn(make_float2(a, b));
    return cv.u;
}
union U4S8 { unsigned u[4]; short8 s; };

__device__ __forceinline__ floatx4 mfma16(short8 a, short8 b, floatx4 c) {
    return __builtin_amdgcn_mfma_f32_16x16x32_bf16(a, b, c, 0, 0, 0);
}

// ---------------------------------------------------------------------------
// Prep: WinT[d][gs] = Win_h[g][d][s]   (coalesced ilog weight rows)
//       M2[g][f][s] = sum_e Wfe[g][f][e]*Win_f[g][e][s]
//       c2b[gs]     = sum_e bfe[g][e]*Win_f[g][e][s] + bin_b[gs]
// blocks 0..63 do WinT; block 64 does M2/c2b.
// ---------------------------------------------------------------------------
__global__ __launch_bounds__(256) void prep_kernel(
    const float* __restrict__ Win_h, const float* __restrict__ Win_f,
    const float* __restrict__ Wfe, const float* __restrict__ bfe,
    const float* __restrict__ bin_b,
    float* __restrict__ WinT, float* __restrict__ M2, float* __restrict__ c2b)
{
    const int tid = threadIdx.x;
    if (blockIdx.x < 64) {
        int idx = blockIdx.x * 256 + tid;      // d*32 + gs
        int d = idx >> 5, gs = idx & 31;
        int g = gs >> 2, s = gs & 3;
        WinT[idx] = Win_h[(size_t)g*DD*SSS + d*SSS + s];
    } else {
        if (tid < GG*FGC*SSS) {                // 128: (g,f,s)
            int g = tid >> 4, f = (tid >> 2) & 3, s = tid & 3;
            float acc = 0.f;
            for (int e = 0; e < FEC; ++e)
                acc += Wfe[(size_t)g*FGC*FEC + f*FEC + e] * Win_f[(size_t)g*FEC*SSS + e*SSS + s];
            M2[tid] = acc;
        } else if (tid < GG*FGC*SSS + GG*SSS) {  // 32: gs
            int gs = tid - GG*FGC*SSS;
            int g = gs >> 2, s = gs & 3;
            float acc = bin_b[gs];
            for (int e = 0; e < FEC; ++e)
                acc += bfe[g*FEC + e] * Win_f[(size_t)g*FEC*SSS + e*SSS + s];
            c2b[gs] = acc;
        }
    }
}

// ---------------------------------------------------------------------------
// Routing stage A (unchanged, round-6 proven): gh = gelu(hidden@Wr1+br1),
// glog = gh@Wr2+br2 -> glog_ws. fp32-exact.
// ---------------------------------------------------------------------------
__global__ __launch_bounds__(512) void gh_glog_kernel(
    const float* __restrict__ hidden,
    const float* __restrict__ Wr1, const float* __restrict__ br1,
    const float* __restrict__ Wr2, const float* __restrict__ br2,
    float* __restrict__ glog_out)
{
    const int t0  = blockIdx.x * RGH_M;
    const int tid = threadIdx.x;
    const int nl  = tid & 63;
    const int ml  = tid >> 6;

    __shared__ float hs[RGH_M][68];
    __shared__ float ghs[RGH_M][260];

    float acc[2][4];
    #pragma unroll
    for (int i = 0; i < 2; ++i)
        #pragma unroll
        for (int j = 0; j < 4; ++j) acc[i][j] = 0.f;

    for (int kc = 0; kc < DD; kc += 64) {
        __syncthreads();
        {
            int r  = tid >> 5;
            int c2 = (tid & 31) * 2;
            float2 v = *(const float2*)(hidden + (size_t)(t0 + r)*DD + kc + c2);
            hs[r][c2]   = v.x;
            hs[r][c2+1] = v.y;
        }
        __syncthreads();
        #pragma unroll 4
        for (int k = 0; k < 64; ++k) {
            const float* wr = Wr1 + (size_t)(kc + k)*RHC + nl;
            float w0 = wr[0], w1 = wr[64], w2 = wr[128], w3 = wr[192];
            float a0 = hs[ml][k], a1 = hs[ml + 8][k];
            acc[0][0] += a0*w0; acc[0][1] += a0*w1; acc[0][2] += a0*w2; acc[0][3] += a0*w3;
            acc[1][0] += a1*w0; acc[1][1] += a1*w1; acc[1][2] += a1*w2; acc[1][3] += a1*w3;
        }
    }
    __syncthreads();
    #pragma unroll
    for (int i = 0; i < 2; ++i) {
        int r = ml + 8*i;
        #pragma unroll
        for (int j = 0; j < 4; ++j) {
            int c = nl + 64*j;
            ghs[r][c] = gelu_exact(acc[i][j] + br1[c]);
        }
    }
    __syncthreads();
    if (tid < RGH_M*GG) {
        int t = tid >> 3, g = tid & 7;
        float s = br2[g];
        #pragma unroll 4
        for (int h = 0; h < RHC; ++h) s += ghs[t][h] * Wr2[h*GG + g];
        glog_out[(size_t)(t0 + t)*GG + g] = s;
    }
}

// ---------------------------------------------------------------------------
// Routing stage B: ilog = hidden@WinT + feat@M2 + c2b + rule, then both
// topk-softmaxes, bucket append, y zeroing. TI=8 tokens/block, grid 512.
// WinT rows are coalesced (lane gs -> 32 consecutive floats).
// ---------------------------------------------------------------------------
__global__ __launch_bounds__(256) void ilog_route(
    const float* __restrict__ hidden, const float* __restrict__ feat,
    const float* __restrict__ WinT, const float* __restrict__ M2,
    const float* __restrict__ c2b,
    const float* __restrict__ glog_ws,
    int* __restrict__ bucket_tok, float* __restrict__ bucket_w,
    int* __restrict__ counts,
    float* __restrict__ y)
{
    const int t0  = blockIdx.x * TI;
    const int tid = threadIdx.x;

    __shared__ float hs[TI][516];        // +4 pad: lanes differing in t avoid same-bank
    __shared__ float featb[TI][GG*FGC];
    __shared__ float ilogb[TI][GG*SSS];
    __shared__ float glogb[TI][GG];
    __shared__ float gwvb[TI][GG];
    __shared__ float scoreb[TI][GG];
    __shared__ float cwvb[TI][GG*SSS];

    for (int i = tid; i < TI*DD; i += 256) {
        int r = i >> 9, c = i & 511;
        hs[r][c] = hidden[(size_t)(t0 + r)*DD + c];
        y[(size_t)(t0 + r)*DD + c] = 0.0f;
    }
    if (tid < TI*GG*FGC) {   // 256
        int r = tid >> 5, c = tid & 31;
        featb[r][c] = feat[(t0 + r)*(GG*FGC) + c];
    }
    if (tid < TI*GG) {       // 64
        int t = tid >> 3, g = tid & 7;
        glogb[t][g] = glog_ws[(size_t)(t0 + t)*GG + g];
    }
    __syncthreads();

    if (tid < TI*GG) {       // score per (t,g)
        int t = tid >> 3, g = tid & 7;
        float s = 0.f;
        #pragma unroll
        for (int f = 0; f < FGC; ++f) s += fminf(fmaxf(featb[t][g*4+f], 0.f), 1.f);
        scoreb[t][g] = s * 0.25f;
    }
    __syncthreads();

    // main dot: thread = (t = tid>>5, gs = tid&31)
    {
        const int t = tid >> 5, gs = tid & 31;
        const int g = gs >> 2, s = gs & 3;
        float acc = 0.f;
        #pragma unroll 8
        for (int k = 0; k < DD; ++k) acc += hs[t][k] * WinT[k*32 + gs];
        const float* m2 = M2 + g*16 + s;     // stride 4 over f
        acc += featb[t][g*4+0]*m2[0] + featb[t][g*4+1]*m2[4]
             + featb[t][g*4+2]*m2[8] + featb[t][g*4+3]*m2[12];
        const float centers[4] = {0.0f, 1.0f/3.0f, 2.0f/3.0f, 1.0f};
        float diff = scoreb[t][g] - centers[s];
        ilogb[t][gs] = acc + c2b[gs] - 16.0f * diff * diff;
    }
    __syncthreads();

    // group top-2 softmax per token
    if (tid < TI) {
        int t = tid;
        float a = -INFINITY, b = -INFINITY;
        #pragma unroll
        for (int g = 0; g < GG; ++g) {
            float v = glogb[t][g];
            if (v > a) { b = a; a = v; } else if (v > b) { b = v; }
        }
        float thresh = b, m = a, sum = 0.f;
        float ex[GG];
        #pragma unroll
        for (int g = 0; g < GG; ++g) {
            float v = glogb[t][g];
            ex[g] = (v >= thresh) ? __expf(v - m) : 0.f;
            sum += ex[g];
        }
        float inv = 1.0f / sum;
        #pragma unroll
        for (int g = 0; g < GG; ++g) gwvb[t][g] = ex[g] * inv;
    }
    // stage top-2 softmax per (t,g)
    if (tid < TI*GG) {
        int t = tid >> 3, g = tid & 7;
        float vv[4] = {ilogb[t][g*4+0], ilogb[t][g*4+1], ilogb[t][g*4+2], ilogb[t][g*4+3]};
        float a = -INFINITY, b = -INFINITY;
        #pragma unroll
        for (int s = 0; s < 4; ++s) {
            float v = vv[s];
            if (v > a) { b = a; a = v; } else if (v > b) { b = v; }
        }
        float thresh = b, m = a, sum = 0.f;
        float ex[4];
        #pragma unroll
        for (int s = 0; s < 4; ++s) {
            ex[s] = (vv[s] >= thresh) ? __expf(vv[s] - m) : 0.f;
            sum += ex[s];
        }
        float inv = 1.0f / sum;
        #pragma unroll
        for (int s = 0; s < 4; ++s) cwvb[t][g*4 + s] = ex[s] * inv;
    }
    __syncthreads();

    if (tid < TI) {
        int t = tid;
        for (int g = 0; g < GG; ++g) {
            float gw = gwvb[t][g];
            if (gw > 0.f) {
                for (int s = 0; s < SSS; ++s) {
                    float w = gw * cwvb[t][g*4 + s];
                    if (w > 0.f) {
                        int ee = g*SSS + s;
                        int pos = atomicAdd(&counts[ee], 1);
                        bucket_tok[ee*NT + pos] = t0 + t;
                        bucket_w[ee*NT + pos]   = w;
                    }
                }
            }
        }
    }
}

// ---------------------------------------------------------------------------
// Expert GEMM: TM=64 tokens/block, 512 threads (8 waves). Waves own disjoint
// n-slices (32 cols ph1, 64 cols ph2) and ALL 4 m-fragments -> per-token
// weight-load instruction count halved vs TM=32. HW pk-cvt for fp32->bf16.
// A-frag: m=lane&15, k=quad*8+j  (LDS [k8][m][8])
// B-frag: n=lane&15, k=quad*8+j  (8 strided fp32 loads + 4 pk-cvt)
// C/D:    col=lane&15, row=quad*4+reg
// ---------------------------------------------------------------------------
__global__ __launch_bounds__(512) void expert_mfma64(
    const float* __restrict__ hidden,
    const float* __restrict__ We1, const float* __restrict__ be1,
    const float* __restrict__ We2, const float* __restrict__ be2,
    const int* __restrict__ bucket_tok, const float* __restrict__ bucket_w,
    const int* __restrict__ counts,
    float* __restrict__ y)
{
    const int e   = blockIdx.y;
    const int cnt = counts[e];
    const int r0  = blockIdx.x * TM;
    if (r0 >= cnt) return;
    const int nrow = min(TM, cnt - r0);
    const int tid  = threadIdx.x;
    const int wave = tid >> 6;          // 0..7
    const int lane = tid & 63;
    const int lm   = lane & 15;
    const int quad = lane >> 4;

    __shared__ short Xc[8 * XC2_STRIDE];    // 64-k chunk x 64 tok, [k8][m][8]
    __shared__ short Hp[32 * HP2_STRIDE];   // 256 h x 64 tok,  [h8][m][8]
    __shared__ int   toks[TM];
    __shared__ float tws[TM];

    if (tid < TM) {
        if (tid < nrow) {
            toks[tid] = bucket_tok[e*NT + r0 + tid];
            tws[tid]  = bucket_w[e*NT + r0 + tid];
        } else { toks[tid] = -1; tws[tid] = 0.f; }
    }
    __syncthreads();

    // ---- phase 1: wave n-slice = wave*32 (nb 0..1); m-frags 0..3 ----
    floatx4 acc[4][2];
    #pragma unroll
    for (int mb = 0; mb < 4; ++mb)
        #pragma unroll
        for (int nb = 0; nb < 2; ++nb)
            acc[mb][nb] = (floatx4){0.f, 0.f, 0.f, 0.f};

    const float* W1 = We1 + (size_t)e * DD * DHC;
    const int xr = tid >> 3;        // token row 0..63
    const int xk = tid & 7;         // k8 group 0..7

    for (int kc = 0; kc < DD; kc += 64) {
        __syncthreads();
        {   // stage X: 64 tok x 64 k -> 8 floats/thread
            const int tk = toks[xr];
            float4 v0 = make_float4(0.f,0.f,0.f,0.f), v1 = v0;
            if (tk >= 0) {
                const float* src = hidden + (size_t)tk*DD + kc + xk*8;
                v0 = *(const float4*)src;
                v1 = *(const float4*)(src + 4);
            }
            U4S8 cv;
            cv.u[0] = pk2(v0.x, v0.y); cv.u[1] = pk2(v0.z, v0.w);
            cv.u[2] = pk2(v1.x, v1.y); cv.u[3] = pk2(v1.z, v1.w);
            *(short8*)(&Xc[xk * XC2_STRIDE + xr * 8]) = cv.s;
        }
        __syncthreads();
        #pragma unroll
        for (int kk = 0; kk < 64; kk += 32) {
            const int k8l = (kk >> 3) + quad;
            short8 a[4];
            #pragma unroll
            for (int mb = 0; mb < 4; ++mb)
                a[mb] = *(const short8*)(&Xc[k8l * XC2_STRIDE + (mb*16 + lm) * 8]);
            const int k0 = kc + k8l*8;
            #pragma unroll
            for (int nb = 0; nb < 2; ++nb) {
                const int n = wave*32 + nb*16 + lm;
                const float* src = W1 + (size_t)k0*DHC + n;
                float f0 = src[0],       f1 = src[DHC],   f2 = src[2*DHC], f3 = src[3*DHC];
                float f4 = src[4*DHC],   f5 = src[5*DHC], f6 = src[6*DHC], f7 = src[7*DHC];
                U4S8 cv;
                cv.u[0] = pk2(f0,f1); cv.u[1] = pk2(f2,f3);
                cv.u[2] = pk2(f4,f5); cv.u[3] = pk2(f6,f7);
                #pragma unroll
                for (int mb = 0; mb < 4; ++mb)
                    acc[mb][nb] = mfma16(a[mb], cv.s, acc[mb][nb]);
            }
        }
    }

    // bias + gelu -> Hp (bf16, A-layout). Waves write disjoint h-slices.
    __syncthreads();
    #pragma unroll
    for (int nb = 0; nb < 2; ++nb) {
        const int h = wave*32 + nb*16 + lm;
        const float b1 = be1[e*DHC + h];
        #pragma unroll
        for (int mb = 0; mb < 4; ++mb) {
            #pragma unroll
            for (int r = 0; r < 4; r += 2) {
                const int m0 = mb*16 + quad*4 + r;
                unsigned u = pk2(gelu_exact(acc[mb][nb][r]   + b1),
                                 gelu_exact(acc[mb][nb][r+1] + b1));
                Hp[(h >> 3) * HP2_STRIDE + m0 * 8 + (h & 7)]     = (short)(u & 0xffff);
                Hp[(h >> 3) * HP2_STRIDE + (m0+1) * 8 + (h & 7)] = (short)(u >> 16);
            }
        }
    }
    __syncthreads();

    // ---- phase 2: wave n-slice = wave*64 (nb 0..3); m-frags 0..3 ----
    floatx4 c[4][4];
    #pragma unroll
    for (int mb = 0; mb < 4; ++mb)
        #pragma unroll
        for (int nb = 0; nb < 4; ++nb)
            c[mb][nb] = (floatx4){0.f, 0.f, 0.f, 0.f};

    const float* W2 = We2 + (size_t)e * DHC * DD;

    for (int kc = 0; kc < DHC; kc += 32) {
        const int k8 = (kc >> 3) + quad;
        short8 a[4];
        #pragma unroll
        for (int mb = 0; mb < 4; ++mb)
            a[mb] = *(const short8*)(&Hp[k8 * HP2_STRIDE + (mb*16 + lm) * 8]);
        const int k0 = k8*8;
        #pragma unroll
        for (int nb = 0; nb < 4; ++nb) {
            const int n = wave*64 + nb*16 + lm;
            const float* src = W2 + (size_t)k0*DD + n;
            float f0 = src[0],      f1 = src[DD],   f2 = src[2*DD], f3 = src[3*DD];
            float f4 = src[4*DD],   f5 = src[5*DD], f6 = src[6*DD], f7 = src[7*DD];
            U4S8 cv;
            cv.u[0] = pk2(f0,f1); cv.u[1] = pk2(f2,f3);
            cv.u[2] = pk2(f4,f5); cv.u[3] = pk2(f6,f7);
            #pragma unroll
            for (int mb = 0; mb < 4; ++mb)
                c[mb][nb] = mfma16(a[mb], cv.s, c[mb][nb]);
        }
    }

    // epilogue: weighted atomicAdd into y (+ be2)
    #pragma unroll
    for (int nb = 0; nb < 4; ++nb) {
        const int col = wave*64 + nb*16 + lm;
        const float b2 = be2[e*DD + col];
        #pragma unroll
        for (int mb = 0; mb < 4; ++mb) {
            #pragma unroll
            for (int r = 0; r < 4; ++r) {
                const int m = mb*16 + quad*4 + r;
                const int tk = toks[m];
                if (tk >= 0)
                    atomicAdd(&y[(size_t)tk*DD + col], tws[m] * (c[mb][nb][r] + b2));
            }
        }
    }
}

extern "C" void kernel_launch(void* const* d_in, const int* in_sizes, int n_in,
                              void* d_out, int out_size, void* d_ws, size_t ws_size,
                              hipStream_t stream) {
    const float* hidden = (const float*)d_in[0];
    const float* feat   = (const float*)d_in[1];
    // d_in[2] = valid_mask (unused)
    const float* Wr1    = (const float*)d_in[3];
    const float* br1    = (const float*)d_in[4];
    const float* Wr2    = (const float*)d_in[5];
    const float* br2    = (const float*)d_in[6];
    const float* Wfe    = (const float*)d_in[7];
    const float* bfe    = (const float*)d_in[8];
    const float* Win_h  = (const float*)d_in[9];
    const float* Win_f  = (const float*)d_in[10];
    const float* bin_b  = (const float*)d_in[11];
    const float* We1    = (const float*)d_in[12];
    const float* be1    = (const float*)d_in[13];
    const float* We2    = (const float*)d_in[14];
    const float* be2    = (const float*)d_in[15];
    float* y = (float*)d_out;

    // workspace ~1.19 MB (proven-safe scale)
    char* ws = (char*)d_ws;
    int*   bucket_tok = (int*)ws;    ws += (size_t)EEC*NT*sizeof(int);    // 512 KB
    float* bucket_w   = (float*)ws;  ws += (size_t)EEC*NT*sizeof(float);  // 512 KB
    float* glog_ws    = (float*)ws;  ws += (size_t)NT*GG*sizeof(float);   // 128 KB
    int*   counts     = (int*)ws;    ws += 256;
    float* WinT       = (float*)ws;  ws += (size_t)DD*EEC*sizeof(float);  // 64 KB
    float* M2         = (float*)ws;  ws += GG*FGC*SSS*sizeof(float);      // 512 B
    float* c2b        = (float*)ws;

    hipMemsetAsync(counts, 0, EEC*sizeof(int), stream);

    prep_kernel<<<65, 256, 0, stream>>>(Win_h, Win_f, Wfe, bfe, bin_b,
                                        WinT, M2, c2b);

    gh_glog_kernel<<<NT/RGH_M, 512, 0, stream>>>(hidden, Wr1, br1, Wr2, br2, glog_ws);

    ilog_route<<<NT/TI, 256, 0, stream>>>(hidden, feat, WinT, M2, c2b, glog_ws,
                                          bucket_tok, bucket_w, counts, y);

    dim3 grid2(NT/TM, EEC);
    expert_mfma64<<<grid2, 512, 0, stream>>>(hidden, We1, be1, We2, be2,
                                             bucket_tok, bucket_w, counts, y);
}

// Round 8
// 400.640 us; speedup vs baseline: 1.2332x; 1.2280x over previous
//
#include <hip/hip_runtime.h>
#include <hip/hip_bf16.h>
#include <math.h>

// Problem constants (fixed by reference)
#define BB   8
#define LL   512
#define DD   512
#define GG   8
#define SSS  4
#define FGC  4
#define FEC  64
#define EEC  32
#define DHC  256
#define RHC  256
#define NT   (BB*LL)   // 4096 tokens
#define TM   32        // tokens per expert tile
#define TR   8         // tokens per fused_route block

#define XC_STRIDE 264  // shorts per k8 group (32*8 + 8 pad; 528 B, 16B-aligned)

typedef __attribute__((ext_vector_type(8))) short short8;
typedef __attribute__((ext_vector_type(4))) float floatx4;

__device__ __forceinline__ float gelu_exact(float x) {
    return 0.5f * x * (1.0f + erff(x * 0.70710678118654752440f));
}

// HW packed fp32->bf16 RNE (v_cvt_pk_bf16_f32); low 16 bits = first arg
__device__ __forceinline__ unsigned pk2(float a, float b) {
    union { __hip_bfloat162 h; unsigned u; } cv;
    cv.h = __float22bfloat162_rn(make_float2(a, b));
    return cv.u;
}
union U4S8 { unsigned u[4]; short8 s; };

__device__ __forceinline__ floatx4 mfma16(short8 a, short8 b, floatx4 c) {
    return __builtin_amdgcn_mfma_f32_16x16x32_bf16(a, b, c, 0, 0, 0);
}

// ---------------------------------------------------------------------------
// Prep: WinT[d][gs] = Win_h[g][d][s]   (coalesced ilog weight rows)
//       M2[g][f][s] = sum_e Wfe[g][f][e]*Win_f[g][e][s]
//       c2b[gs]     = sum_e bfe[g][e]*Win_f[g][e][s] + bin_b[gs]
// ---------------------------------------------------------------------------
__global__ __launch_bounds__(256) void prep_kernel(
    const float* __restrict__ Win_h, const float* __restrict__ Win_f,
    const float* __restrict__ Wfe, const float* __restrict__ bfe,
    const float* __restrict__ bin_b,
    float* __restrict__ WinT, float* __restrict__ M2, float* __restrict__ c2b)
{
    const int tid = threadIdx.x;
    if (blockIdx.x < 64) {
        int idx = blockIdx.x * 256 + tid;      // d*32 + gs
        int d = idx >> 5, gs = idx & 31;
        int g = gs >> 2, s = gs & 3;
        WinT[idx] = Win_h[(size_t)g*DD*SSS + d*SSS + s];
    } else {
        if (tid < GG*FGC*SSS) {                // 128: (g,f,s)
            int g = tid >> 4, f = (tid >> 2) & 3, s = tid & 3;
            float acc = 0.f;
            for (int e = 0; e < FEC; ++e)
                acc += Wfe[(size_t)g*FGC*FEC + f*FEC + e] * Win_f[(size_t)g*FEC*SSS + e*SSS + s];
            M2[tid] = acc;
        } else if (tid < GG*FGC*SSS + GG*SSS) {  // 32: gs
            int gs = tid - GG*FGC*SSS;
            int g = gs >> 2, s = gs & 3;
            float acc = bin_b[gs];
            for (int e = 0; e < FEC; ++e)
                acc += bfe[g*FEC + e] * Win_f[(size_t)g*FEC*SSS + e*SSS + s];
            c2b[gs] = acc;
        }
    }
}

// ---------------------------------------------------------------------------
// Fused routing: per block of TR=8 tokens (grid 512, 256 thr):
//  hs stage + y zero -> gh(=gelu(h@Wr1+br1)) -> glog(gh@Wr2+br2)
//  -> ilog(h@WinT + feat@M2 + c2b + rule) -> both top-2 softmaxes -> buckets.
// All fp32, per-token topk code identical to passing rounds.
// ---------------------------------------------------------------------------
__global__ __launch_bounds__(256) void fused_route(
    const float* __restrict__ hidden, const float* __restrict__ feat,
    const float* __restrict__ Wr1, const float* __restrict__ br1,
    const float* __restrict__ Wr2, const float* __restrict__ br2,
    const float* __restrict__ WinT, const float* __restrict__ M2,
    const float* __restrict__ c2b,
    int* __restrict__ bucket_tok, float* __restrict__ bucket_w,
    int* __restrict__ counts,
    float* __restrict__ y)
{
    const int t0  = blockIdx.x * TR;
    const int tid = threadIdx.x;

    __shared__ float hs[TR][DD];        // 16 KB
    __shared__ float ghs[TR][RHC+4];    // 8.1 KB
    __shared__ float featb[TR][GG*FGC];
    __shared__ float glogb[TR][GG];
    __shared__ float gwvb[TR][GG];
    __shared__ float scoreb[TR][GG];
    __shared__ float ilogb[TR][GG*SSS];
    __shared__ float cwvb[TR][GG*SSS];

    // stage hidden + zero y
    for (int i = tid; i < TR*DD; i += 256) {
        int r = i >> 9, c = i & 511;
        hs[r][c] = hidden[(size_t)(t0 + r)*DD + c];
        y[(size_t)(t0 + r)*DD + c] = 0.0f;
    }
    if (tid < TR*GG*FGC) {   // 256
        int r = tid >> 5, c = tid & 31;
        featb[r][c] = feat[(t0 + r)*(GG*FGC) + c];
    }
    __syncthreads();

    if (tid < TR*GG) {       // score per (t,g)
        int t = tid >> 3, g = tid & 7;
        float s = 0.f;
        #pragma unroll
        for (int f = 0; f < FGC; ++f) s += fminf(fmaxf(featb[t][g*4+f], 0.f), 1.f);
        scoreb[t][g] = s * 0.25f;
    }

    // ---- gh: thread owns Wr1 column h=tid for all 8 tokens ----
    {
        float acc[TR];
        float b = br1[tid];
        #pragma unroll
        for (int t = 0; t < TR; ++t) acc[t] = b;
        #pragma unroll 2
        for (int k = 0; k < DD; k += 4) {
            float w0 = Wr1[(size_t)k*RHC + tid];
            float w1 = Wr1[(size_t)(k+1)*RHC + tid];
            float w2 = Wr1[(size_t)(k+2)*RHC + tid];
            float w3 = Wr1[(size_t)(k+3)*RHC + tid];
            #pragma unroll
            for (int t = 0; t < TR; ++t) {
                float4 h = *(const float4*)(&hs[t][k]);
                acc[t] += h.x*w0 + h.y*w1 + h.z*w2 + h.w*w3;
            }
        }
        #pragma unroll
        for (int t = 0; t < TR; ++t) ghs[t][tid] = gelu_exact(acc[t]);
    }
    __syncthreads();

    // ---- glog: thread = (t,g), 64 threads ----
    if (tid < TR*GG) {
        int t = tid >> 3, g = tid & 7;
        float s = br2[g];
        #pragma unroll 4
        for (int h = 0; h < RHC; ++h) s += ghs[t][h] * Wr2[h*GG + g];
        glogb[t][g] = s;
    }

    // ---- ilog: thread = (t = tid>>5, gs = tid&31) ----
    {
        const int t = tid >> 5, gs = tid & 31;
        const int g = gs >> 2, s = gs & 3;
        float acc = 0.f;
        #pragma unroll 8
        for (int k = 0; k < DD; ++k) acc += hs[t][k] * WinT[k*32 + gs];
        const float* m2 = M2 + g*16 + s;     // stride 4 over f
        acc += featb[t][g*4+0]*m2[0] + featb[t][g*4+1]*m2[4]
             + featb[t][g*4+2]*m2[8] + featb[t][g*4+3]*m2[12];
        const float centers[4] = {0.0f, 1.0f/3.0f, 2.0f/3.0f, 1.0f};
        float diff = scoreb[t][g] - centers[s];
        ilogb[t][gs] = acc + c2b[gs] - 16.0f * diff * diff;
    }
    __syncthreads();

    // group top-2 softmax per token
    if (tid < TR) {
        int t = tid;
        float a = -INFINITY, b = -INFINITY;
        #pragma unroll
        for (int g = 0; g < GG; ++g) {
            float v = glogb[t][g];
            if (v > a) { b = a; a = v; } else if (v > b) { b = v; }
        }
        float thresh = b, m = a, sum = 0.f;
        float ex[GG];
        #pragma unroll
        for (int g = 0; g < GG; ++g) {
            float v = glogb[t][g];
            ex[g] = (v >= thresh) ? __expf(v - m) : 0.f;
            sum += ex[g];
        }
        float inv = 1.0f / sum;
        #pragma unroll
        for (int g = 0; g < GG; ++g) gwvb[t][g] = ex[g] * inv;
    }
    // stage top-2 softmax per (t,g)
    if (tid < TR*GG) {
        int t = tid >> 3, g = tid & 7;
        float vv[4] = {ilogb[t][g*4+0], ilogb[t][g*4+1], ilogb[t][g*4+2], ilogb[t][g*4+3]};
        float a = -INFINITY, b = -INFINITY;
        #pragma unroll
        for (int s = 0; s < 4; ++s) {
            float v = vv[s];
            if (v > a) { b = a; a = v; } else if (v > b) { b = v; }
        }
        float thresh = b, m = a, sum = 0.f;
        float ex[4];
        #pragma unroll
        for (int s = 0; s < 4; ++s) {
            ex[s] = (vv[s] >= thresh) ? __expf(vv[s] - m) : 0.f;
            sum += ex[s];
        }
        float inv = 1.0f / sum;
        #pragma unroll
        for (int s = 0; s < 4; ++s) cwvb[t][g*4 + s] = ex[s] * inv;
    }
    __syncthreads();

    if (tid < TR) {
        int t = tid;
        for (int g = 0; g < GG; ++g) {
            float gw = gwvb[t][g];
            if (gw > 0.f) {
                for (int s = 0; s < SSS; ++s) {
                    float w = gw * cwvb[t][g*4 + s];
                    if (w > 0.f) {
                        int ee = g*SSS + s;
                        int pos = atomicAdd(&counts[ee], 1);
                        bucket_tok[ee*NT + pos] = t0 + t;
                        bucket_w[ee*NT + pos]   = w;
                    }
                }
            }
        }
    }
}

// ---------------------------------------------------------------------------
// Expert GEMM v3: TM=32, 256 thr, 4 waves. X tile fully resident in LDS ->
// ZERO barriers in both K-loops (W loads pipeline freely across MFMAs).
// 1-D grid with XCD-pinned mapping: e = blockIdx.x & 31 -> all tiles of an
// expert land on XCD e%8 (round-robin dispatch); 4 experts x 1 MB = 4 MB L2.
// A-frag: m=lane&15, k=quad*8+j  (LDS [k8][m][8])
// B-frag: n=lane&15, k=quad*8+j  (8 strided fp32 loads, batched, + pk-cvt)
// C/D:    col=lane&15, row=quad*4+reg
// ---------------------------------------------------------------------------
__global__ __launch_bounds__(256) void expert_mfma3(
    const float* __restrict__ hidden,
    const float* __restrict__ We1, const float* __restrict__ be1,
    const float* __restrict__ We2, const float* __restrict__ be2,
    const int* __restrict__ bucket_tok, const float* __restrict__ bucket_w,
    const int* __restrict__ counts,
    float* __restrict__ y)
{
    const int e    = blockIdx.x & 31;
    const int tile = blockIdx.x >> 5;
    const int cnt  = counts[e];
    const int r0   = tile * TM;
    if (r0 >= cnt) return;
    const int nrow = min(TM, cnt - r0);
    const int tid  = threadIdx.x;
    const int wave = tid >> 6;
    const int lane = tid & 63;
    const int lm   = lane & 15;
    const int quad = lane >> 4;

    __shared__ short Xp[64 * XC_STRIDE];   // full X tile: 64 k8 x 32 m x 8
    __shared__ short Hp[32 * XC_STRIDE];   // H: 32 h8 x 32 m x 8
    __shared__ int   toks[TM];
    __shared__ float tws[TM];

    if (tid < TM) {
        if (tid < nrow) {
            toks[tid] = bucket_tok[e*NT + r0 + tid];
            tws[tid]  = bucket_w[e*NT + r0 + tid];
        } else { toks[tid] = -1; tws[tid] = 0.f; }
    }
    __syncthreads();

    // stage ALL of X (32 tok x 512 k) as bf16 in A-layout
    {
        const int xr = tid >> 3;      // token 0..31
        const int xk = tid & 7;       // k8 subgroup
        const int tk = toks[xr];
        const float* src = hidden + (size_t)(tk < 0 ? 0 : tk)*DD;
        #pragma unroll
        for (int i = 0; i < 8; ++i) {
            const int k8 = xk + 8*i;
            float4 v0 = make_float4(0.f,0.f,0.f,0.f), v1 = v0;
            if (tk >= 0) {
                v0 = *(const float4*)(src + k8*8);
                v1 = *(const float4*)(src + k8*8 + 4);
            }
            U4S8 cv;
            cv.u[0] = pk2(v0.x, v0.y); cv.u[1] = pk2(v0.z, v0.w);
            cv.u[2] = pk2(v1.x, v1.y); cv.u[3] = pk2(v1.z, v1.w);
            *(short8*)(&Xp[k8 * XC_STRIDE + xr * 8]) = cv.s;
        }
    }
    __syncthreads();

    // ---- phase 1: H = gelu(X @ We1 + be1); wave owns 64 cols; NO barriers ----
    floatx4 acc[2][4];
    #pragma unroll
    for (int mb = 0; mb < 2; ++mb)
        #pragma unroll
        for (int nb = 0; nb < 4; ++nb)
            acc[mb][nb] = (floatx4){0.f, 0.f, 0.f, 0.f};

    const float* W1 = We1 + (size_t)e * DD * DHC;

    for (int i = 0; i < 16; ++i) {
        const int k8 = i*4 + quad;
        short8 a0 = *(const short8*)(&Xp[k8 * XC_STRIDE + lm * 8]);
        short8 a1 = *(const short8*)(&Xp[k8 * XC_STRIDE + (16 + lm) * 8]);
        float wreg[4][8];
        #pragma unroll
        for (int nb = 0; nb < 4; ++nb) {
            const float* s = W1 + (size_t)(k8*8)*DHC + wave*64 + nb*16 + lm;
            #pragma unroll
            for (int j = 0; j < 8; ++j) wreg[nb][j] = s[(size_t)j*DHC];
        }
        #pragma unroll
        for (int nb = 0; nb < 4; ++nb) {
            U4S8 cv;
            cv.u[0] = pk2(wreg[nb][0], wreg[nb][1]);
            cv.u[1] = pk2(wreg[nb][2], wreg[nb][3]);
            cv.u[2] = pk2(wreg[nb][4], wreg[nb][5]);
            cv.u[3] = pk2(wreg[nb][6], wreg[nb][7]);
            acc[0][nb] = mfma16(a0, cv.s, acc[0][nb]);
            acc[1][nb] = mfma16(a1, cv.s, acc[1][nb]);
        }
    }

    // bias + gelu -> Hp (A-layout); waves write disjoint h-slices
    #pragma unroll
    for (int nb = 0; nb < 4; ++nb) {
        const int h = wave*64 + nb*16 + lm;
        const float b1 = be1[e*DHC + h];
        #pragma unroll
        for (int mb = 0; mb < 2; ++mb) {
            #pragma unroll
            for (int r = 0; r < 4; r += 2) {
                const int m0 = mb*16 + quad*4 + r;
                unsigned u = pk2(gelu_exact(acc[mb][nb][r]   + b1),
                                 gelu_exact(acc[mb][nb][r+1] + b1));
                Hp[(h >> 3) * XC_STRIDE + m0 * 8 + (h & 7)]     = (short)(u & 0xffff);
                Hp[(h >> 3) * XC_STRIDE + (m0+1) * 8 + (h & 7)] = (short)(u >> 16);
            }
        }
    }
    __syncthreads();   // the only barrier between phases

    // ---- phase 2: Y += w*(H @ We2 + be2); wave owns 128 cols; NO barriers ----
    floatx4 c[2][8];
    #pragma unroll
    for (int mb = 0; mb < 2; ++mb)
        #pragma unroll
        for (int nb = 0; nb < 8; ++nb)
            c[mb][nb] = (floatx4){0.f, 0.f, 0.f, 0.f};

    const float* W2 = We2 + (size_t)e * DHC * DD;

    for (int i = 0; i < 8; ++i) {
        const int k8 = i*4 + quad;
        short8 a0 = *(const short8*)(&Hp[k8 * XC_STRIDE + lm * 8]);
        short8 a1 = *(const short8*)(&Hp[k8 * XC_STRIDE + (16 + lm) * 8]);
        #pragma unroll
        for (int half = 0; half < 2; ++half) {
            float wreg[4][8];
            #pragma unroll
            for (int nb4 = 0; nb4 < 4; ++nb4) {
                const int n = wave*128 + (half*4 + nb4)*16 + lm;
                const float* s = W2 + (size_t)(k8*8)*DD + n;
                #pragma unroll
                for (int j = 0; j < 8; ++j) wreg[nb4][j] = s[(size_t)j*DD];
            }
            #pragma unroll
            for (int nb4 = 0; nb4 < 4; ++nb4) {
                const int nb = half*4 + nb4;
                U4S8 cv;
                cv.u[0] = pk2(wreg[nb4][0], wreg[nb4][1]);
                cv.u[1] = pk2(wreg[nb4][2], wreg[nb4][3]);
                cv.u[2] = pk2(wreg[nb4][4], wreg[nb4][5]);
                cv.u[3] = pk2(wreg[nb4][6], wreg[nb4][7]);
                c[0][nb] = mfma16(a0, cv.s, c[0][nb]);
                c[1][nb] = mfma16(a1, cv.s, c[1][nb]);
            }
        }
    }

    // epilogue: weighted atomicAdd into y (+ be2)
    #pragma unroll
    for (int nb = 0; nb < 8; ++nb) {
        const int col = wave*128 + nb*16 + lm;
        const float b2 = be2[e*DD + col];
        #pragma unroll
        for (int mb = 0; mb < 2; ++mb) {
            #pragma unroll
            for (int r = 0; r < 4; ++r) {
                const int m = mb*16 + quad*4 + r;
                const int tk = toks[m];
                if (tk >= 0)
                    atomicAdd(&y[(size_t)tk*DD + col], tws[m] * (c[mb][nb][r] + b2));
            }
        }
    }
}

extern "C" void kernel_launch(void* const* d_in, const int* in_sizes, int n_in,
                              void* d_out, int out_size, void* d_ws, size_t ws_size,
                              hipStream_t stream) {
    const float* hidden = (const float*)d_in[0];
    const float* feat   = (const float*)d_in[1];
    // d_in[2] = valid_mask (unused)
    const float* Wr1    = (const float*)d_in[3];
    const float* br1    = (const float*)d_in[4];
    const float* Wr2    = (const float*)d_in[5];
    const float* br2    = (const float*)d_in[6];
    const float* Wfe    = (const float*)d_in[7];
    const float* bfe    = (const float*)d_in[8];
    const float* Win_h  = (const float*)d_in[9];
    const float* Win_f  = (const float*)d_in[10];
    const float* bin_b  = (const float*)d_in[11];
    const float* We1    = (const float*)d_in[12];
    const float* be1    = (const float*)d_in[13];
    const float* We2    = (const float*)d_in[14];
    const float* be2    = (const float*)d_in[15];
    float* y = (float*)d_out;

    // workspace ~1.08 MB (proven-safe scale)
    char* ws = (char*)d_ws;
    int*   bucket_tok = (int*)ws;    ws += (size_t)EEC*NT*sizeof(int);    // 512 KB
    float* bucket_w   = (float*)ws;  ws += (size_t)EEC*NT*sizeof(float);  // 512 KB
    int*   counts     = (int*)ws;    ws += 256;
    float* WinT       = (float*)ws;  ws += (size_t)DD*EEC*sizeof(float);  // 64 KB
    float* M2         = (float*)ws;  ws += GG*FGC*SSS*sizeof(float);      // 512 B
    float* c2b        = (float*)ws;

    hipMemsetAsync(counts, 0, EEC*sizeof(int), stream);

    prep_kernel<<<65, 256, 0, stream>>>(Win_h, Win_f, Wfe, bfe, bin_b,
                                        WinT, M2, c2b);

    fused_route<<<NT/TR, 256, 0, stream>>>(hidden, feat, Wr1, br1, Wr2, br2,
                                           WinT, M2, c2b,
                                           bucket_tok, bucket_w, counts, y);

    expert_mfma3<<<(NT/TM)*EEC, 256, 0, stream>>>(hidden, We1, be1, We2, be2,
                                                  bucket_tok, bucket_w, counts, y);
}